// Round 4
// baseline (639.645 us; speedup 1.0000x reference)
//
#include <hip/hip_runtime.h>
#include <hip/hip_bf16.h>

typedef unsigned short u16;
typedef unsigned int   u32;
typedef unsigned long long u64;
typedef __attribute__((ext_vector_type(8))) short bf16x8;
typedef __attribute__((ext_vector_type(4))) float f32x4;

#define NNODES 50000
#define PADM   50176          // 256 * 196

#define GAS __attribute__((address_space(1)))
#define LAS __attribute__((address_space(3)))

__device__ __forceinline__ u16 f32_bf16_rne(float x) {
    u32 u = __float_as_uint(x);
    return (u16)((u + 0x7fffu + ((u >> 16) & 1u)) >> 16);
}
__device__ __forceinline__ float bf16_f32(u16 h) {
    return __uint_as_float(((u32)h) << 16);
}
__device__ __forceinline__ void barx() {
    asm volatile("" ::: "memory");
    __builtin_amdgcn_s_barrier();
    asm volatile("" ::: "memory");
}

// ---------------- CSR build ----------------

__global__ void k_zero_cnt(int* __restrict__ cnt, int n) {
    int i = blockIdx.x * 256 + threadIdx.x;
    if (i < n) cnt[i] = 0;
}

__global__ void k_count(const int* __restrict__ dst, int E, int* __restrict__ cnt) {
    int e = blockIdx.x * 256 + threadIdx.x;
    if (e < E) atomicAdd(&cnt[dst[e]], 1);
}

__global__ void k_dinv(const int* __restrict__ cnt, float* __restrict__ dinv, int n) {
    int i = blockIdx.x * 256 + threadIdx.x;
    if (i < n) dinv[i] = rsqrtf((float)(cnt[i] + 1));   // +1 self loop
}

__global__ __launch_bounds__(1024) void k_scan(const int* __restrict__ cnt, int n,
                                               int* __restrict__ offs, int* __restrict__ cursor) {
    __shared__ int sums[1024];
    int t = threadIdx.x;
    int per = (n + 1023) / 1024;
    int start = t * per;
    int end = start + per; if (end > n) end = n;
    int s = 0;
    for (int i = start; i < end; ++i) s += cnt[i];
    sums[t] = s;
    __syncthreads();
    for (int d = 1; d < 1024; d <<= 1) {
        int v = (t >= d) ? sums[t - d] : 0;
        __syncthreads();
        sums[t] += v;
        __syncthreads();
    }
    int base = (t == 0) ? 0 : sums[t - 1];
    for (int i = start; i < end; ++i) {
        offs[i] = base; cursor[i] = base;
        base += cnt[i];
    }
    if (t == 1023) offs[n] = sums[1023];
}

__global__ void k_fill(const int* __restrict__ src, const int* __restrict__ dst, int E,
                       int* __restrict__ cursor, const float* __restrict__ dinv,
                       int* __restrict__ csr_src, float* __restrict__ csr_w) {
    int e = blockIdx.x * 256 + threadIdx.x;
    if (e < E) {
        int s = src[e], d = dst[e];
        int slot = atomicAdd(&cursor[d], 1);
        csr_src[slot] = s;
        csr_w[slot] = dinv[s] * dinv[d];
    }
}

// ---------------- weight split: W[N][K] f32 -> [N][2K] bf16 [hi|lo] ----------------

__global__ void k_splitW(const float* __restrict__ W, u16* __restrict__ W2, int total, int K) {
    int i = blockIdx.x * 256 + threadIdx.x;
    if (i >= total) return;
    int n = i / K, k = i - n * K;
    float w = W[i];
    u16 hi = f32_bf16_rne(w);
    u16 lo = f32_bf16_rne(w - bf16_f32(hi));
    W2[(size_t)n * (2 * K) + k] = hi;
    W2[(size_t)n * (2 * K) + K + k] = lo;
}

// ---------------- aggregation (fp32 gather, 4-wide ILP) + split-bf16 output ----------------

template <int V> struct VecT;
template <> struct VecT<2> { using T = float2; };
template <> struct VecT<4> { using T = float4; };

template <int C>
__global__ __launch_bounds__(256) void k_aggregate_split(
    const float* __restrict__ x,
    const int* __restrict__ offs,
    const int* __restrict__ csr_src,
    const float* __restrict__ csr_w,
    const float* __restrict__ dinv,
    u16* __restrict__ out2,            // [PADM][2C] bf16 [hi(C)|lo(C)]
    int nvalid, int padm)
{
    constexpr int V = C / 64;
    using VT = typename VecT<V>::T;
    int wave = threadIdx.x >> 6;
    int lane = threadIdx.x & 63;
    int node = blockIdx.x * 4 + wave;
    if (node >= padm) return;

    float acc[V];
#pragma unroll
    for (int v = 0; v < V; ++v) acc[v] = 0.f;

    if (node < nvalid) {
        float di = dinv[node];
        float ws = di * di;
        VT xv = *(const VT*)(x + (size_t)node * C + lane * V);
        const float* xp = (const float*)&xv;
#pragma unroll
        for (int v = 0; v < V; ++v) acc[v] = ws * xp[v];

        int j0 = offs[node], j1 = offs[node + 1];
        int j = j0;
        for (; j + 4 <= j1; j += 4) {
            int s0 = csr_src[j],     s1 = csr_src[j + 1];
            int s2 = csr_src[j + 2], s3 = csr_src[j + 3];
            float w0 = csr_w[j],     w1 = csr_w[j + 1];
            float w2 = csr_w[j + 2], w3 = csr_w[j + 3];
            VT r0 = *(const VT*)(x + (size_t)s0 * C + lane * V);
            VT r1 = *(const VT*)(x + (size_t)s1 * C + lane * V);
            VT r2 = *(const VT*)(x + (size_t)s2 * C + lane * V);
            VT r3 = *(const VT*)(x + (size_t)s3 * C + lane * V);
            const float* p0 = (const float*)&r0;
            const float* p1 = (const float*)&r1;
            const float* p2 = (const float*)&r2;
            const float* p3 = (const float*)&r3;
#pragma unroll
            for (int v = 0; v < V; ++v) {
                acc[v] = fmaf(w0, p0[v], acc[v]);
                acc[v] = fmaf(w1, p1[v], acc[v]);
                acc[v] = fmaf(w2, p2[v], acc[v]);
                acc[v] = fmaf(w3, p3[v], acc[v]);
            }
        }
        for (; j + 2 <= j1; j += 2) {
            int s0 = csr_src[j], s1 = csr_src[j + 1];
            float w0 = csr_w[j], w1 = csr_w[j + 1];
            VT r0 = *(const VT*)(x + (size_t)s0 * C + lane * V);
            VT r1 = *(const VT*)(x + (size_t)s1 * C + lane * V);
            const float* p0 = (const float*)&r0;
            const float* p1 = (const float*)&r1;
#pragma unroll
            for (int v = 0; v < V; ++v) {
                acc[v] = fmaf(w0, p0[v], acc[v]);
                acc[v] = fmaf(w1, p1[v], acc[v]);
            }
        }
        for (; j < j1; ++j) {
            int s0 = csr_src[j];
            float w0 = csr_w[j];
            VT r0 = *(const VT*)(x + (size_t)s0 * C + lane * V);
            const float* p0 = (const float*)&r0;
#pragma unroll
            for (int v = 0; v < V; ++v) acc[v] = fmaf(w0, p0[v], acc[v]);
        }
    }

    u16 hi[V], lo[V];
#pragma unroll
    for (int v = 0; v < V; ++v) {
        hi[v] = f32_bf16_rne(acc[v]);
        lo[v] = f32_bf16_rne(acc[v] - bf16_f32(hi[v]));
    }
    u16* po = out2 + (size_t)node * (2 * C) + lane * V;
    if (V == 2) {
        u32 hw = (u32)hi[0] | ((u32)hi[1] << 16);
        u32 lw = (u32)lo[0] | ((u32)lo[1] << 16);
        *(u32*)po = hw;
        *(u32*)(po + C) = lw;
    } else {
        u64 hw = (u64)hi[0] | ((u64)hi[1] << 16) | ((u64)hi[2] << 32) | ((u64)hi[3] << 48);
        u64 lw = (u64)lo[0] | ((u64)lo[1] << 16) | ((u64)lo[2] << 32) | ((u64)lo[3] << 48);
        *(u64*)po = hw;
        *(u64*)(po + C) = lw;
    }
}

// ---------------- 128-tile MFMA GEMM (layer 1 only) ----------------

template <int EPI>
__global__ __launch_bounds__(256, 4) void k_mfma_gemm(
    const u16* __restrict__ A2,
    const u16* __restrict__ W2,
    const float* __restrict__ bias,
    float* __restrict__ Cf,
    u16* __restrict__ Cs,
    int N, int K, int Mvalid, int nby)
{
    __shared__ u16 At[128 * 64];
    __shared__ u16 Bt[128 * 64];

    const int nwg = gridDim.x;
    const int orig = blockIdx.x;
    const int q8 = nwg >> 3, r8 = nwg & 7;
    const int xcd = orig & 7, slot = orig >> 3;
    const int L = (xcd < r8 ? xcd * (q8 + 1) : r8 * (q8 + 1) + (xcd - r8) * q8) + slot;
    const int by = L % nby;
    const int bx = L / nby;
    const int bm0 = bx * 128;
    const int bn0 = by * 128;
    const int tid = threadIdx.x;
    const int lane = tid & 63;
    const int w = tid >> 6, wr = w >> 1, wc = w & 1;
    const int g = lane >> 4, rl = lane & 15;
    const int K2 = 2 * K;

    f32x4 acc[4][4];
#pragma unroll
    for (int i = 0; i < 4; ++i)
#pragma unroll
        for (int j = 0; j < 4; ++j) {
            acc[i][j][0] = 0.f; acc[i][j][1] = 0.f; acc[i][j][2] = 0.f; acc[i][j][3] = 0.f;
        }

    size_t aoff[4], boff[4];
    int ldsb[4];
#pragma unroll
    for (int r = 0; r < 4; ++r) {
        int a = r * 4096 + tid * 16;
        int row = a >> 7;
        int c = a & 127;
        int cs = c ^ ((row & 7) << 4);
        int ce = (cs < 64) ? (cs >> 1) : (K + ((cs - 64) >> 1));
        aoff[r] = (size_t)(bm0 + row) * K2 + ce;
        boff[r] = (size_t)(bn0 + row) * K2 + ce;
        ldsb[r] = a;
    }

    for (int k0 = 0; k0 < K; k0 += 32) {
#pragma unroll
        for (int r = 0; r < 4; ++r) {
            __builtin_amdgcn_global_load_lds(
                (const GAS void*)(A2 + aoff[r] + k0),
                (LAS void*)((char*)At + ldsb[r]), 16, 0, 0);
            __builtin_amdgcn_global_load_lds(
                (const GAS void*)(W2 + boff[r] + k0),
                (LAS void*)((char*)Bt + ldsb[r]), 16, 0, 0);
        }
        __syncthreads();

        bf16x8 ah[4], al[4];
#pragma unroll
        for (int m = 0; m < 4; ++m) {
            int row = wr * 64 + m * 16 + rl;
            int sw = (row & 7) << 4;
            const char* base = (const char*)At + row * 128;
            ah[m] = *(const bf16x8*)(base + ((g * 16) ^ sw));
            al[m] = *(const bf16x8*)(base + ((64 + g * 16) ^ sw));
        }
#pragma unroll
        for (int n = 0; n < 4; ++n) {
            int row = wc * 64 + n * 16 + rl;
            int sw = (row & 7) << 4;
            const char* base = (const char*)Bt + row * 128;
            bf16x8 bh = *(const bf16x8*)(base + ((g * 16) ^ sw));
            bf16x8 bl = *(const bf16x8*)(base + ((64 + g * 16) ^ sw));
#pragma unroll
            for (int m = 0; m < 4; ++m) {
                acc[m][n] = __builtin_amdgcn_mfma_f32_16x16x32_bf16(ah[m], bh, acc[m][n], 0, 0, 0);
                acc[m][n] = __builtin_amdgcn_mfma_f32_16x16x32_bf16(al[m], bh, acc[m][n], 0, 0, 0);
                acc[m][n] = __builtin_amdgcn_mfma_f32_16x16x32_bf16(ah[m], bl, acc[m][n], 0, 0, 0);
            }
        }
        __syncthreads();
    }

#pragma unroll
    for (int n = 0; n < 4; ++n) {
        int col = bn0 + wc * 64 + n * 16 + rl;
        float bv = bias[col];
#pragma unroll
        for (int m = 0; m < 4; ++m) {
            int row0 = bm0 + wr * 64 + m * 16 + g * 4;
#pragma unroll
            for (int q = 0; q < 4; ++q) {
                int row = row0 + q;
                float v = acc[m][n][q] + bv;
                if (EPI == 0) {
                    Cf[(size_t)row * N + col] = fmaxf(v, 0.f);
                } else if (EPI == 1) {
                    float rv = fmaxf(v, 0.f);
                    u16 hi = f32_bf16_rne(rv);
                    u16 lo = f32_bf16_rne(rv - bf16_f32(hi));
                    Cs[(size_t)row * (2 * N) + col] = hi;
                    Cs[(size_t)row * (2 * N) + N + col] = lo;
                } else {
                    if (row < Mvalid) Cf[(size_t)row * N + col] = v;
                }
            }
        }
    }
}

// ---------------- 256-tile 8-phase MFMA GEMM (T2+T3+T4+T5) ----------------
// Logical bf16 GEMM over K_ext = 3K with per-tile segment remap:
//   A segments {hi@0, lo@K, hi@0}, B segments {hi@0, hi@0, lo@K}
// -> Ah*Bh + Al*Bh + Ah*Bl, identical math to the 128-tile kernel.
// 512 threads = 8 waves (2M x 4N); per-wave C = 128x64 (frag grid m=0..7, n=0..3,
// interleaved: C-row frag = m*2+wr, C-col frag = n*4+wc).
// LDS 128 KiB: buf[2] { A[256][128B] , B[256][128B] }, XOR-swizzled rows.

#define ISSUE8(s, wbuf, offA, offB)                                              \
    __builtin_amdgcn_global_load_lds(                                            \
        (const GAS void*)(((((s) >> 1) & 1) ? W2 : A2) + gb[s] +                 \
                          ((((s) >> 1) & 1) ? (offB) : (offA))),                 \
        (LAS void*)(smem + (wbuf) * 65536 + lds8[s]), 16, 0, 0)

#define RD_A8(dst, m, rbuf) do {                                                 \
    const char* _b = smem + (rbuf) * 65536 + (((m) * 2 + wr) * 16 + rl) * 128;   \
    dst[0] = *(const bf16x8*)(_b + colb0);                                       \
    dst[1] = *(const bf16x8*)(_b + colb1); } while (0)

#define RD_B8(dst, n, rbuf) do {                                                 \
    const char* _b = smem + (rbuf) * 65536 + 32768 +                             \
                     (((n) * 4 + wc) * 16 + rl) * 128;                           \
    dst[0] = *(const bf16x8*)(_b + colb0);                                       \
    dst[1] = *(const bf16x8*)(_b + colb1); } while (0)

#define MM8(qm, qn, AF, BF)                                                      \
    _Pragma("unroll") for (int ks = 0; ks < 2; ++ks)                             \
    _Pragma("unroll") for (int mm = 0; mm < 4; ++mm)                             \
    _Pragma("unroll") for (int nn = 0; nn < 2; ++nn)                             \
        acc[(qm) * 4 + mm][(qn) * 2 + nn] = __builtin_amdgcn_mfma_f32_16x16x32_bf16( \
            AF[mm][ks], BF[nn][ks], acc[(qm) * 4 + mm][(qn) * 2 + nn], 0, 0, 0);

template <int EPI>
__global__ __launch_bounds__(512, 1) void k_gemm8(
    const u16* __restrict__ A2,
    const u16* __restrict__ W2,
    const float* __restrict__ bias,
    float* __restrict__ Cf,
    u16* __restrict__ Cs,
    int N, int K, int Mvalid, int nbn)
{
    extern __shared__ char smem[];   // 131072 B

    const int nwg = gridDim.x;
    const int orig = blockIdx.x;
    const int q8 = nwg >> 3, r8 = nwg & 7;
    const int xcd = orig & 7, slot = orig >> 3;
    const int L = (xcd < r8 ? xcd * (q8 + 1) : r8 * (q8 + 1) + (xcd - r8) * q8) + slot;
    const int by = L % nbn;
    const int bx = L / nbn;
    const int bm0 = bx * 256, bn0 = by * 256;

    const int tid = threadIdx.x;
    const int lane = tid & 63;
    const int w = tid >> 6;
    const int wr = w >> 2;           // 0..1
    const int wc = w & 3;            // 0..3
    const int g = lane >> 4, rl = lane & 15;
    const int K2 = 2 * K;
    const int NT = (3 * K) >> 6;

    const int swz = (rl & 7) << 4;
    const int colb0 = (g * 16) ^ swz;
    const int colb1 = (64 + g * 16) ^ swz;

    // staging slots: H0=A-half0 (s0,1), H1=B-half0 (s2,3), H2=A-half1 (s4,5), H3=B-half1 (s6,7)
    size_t gb[8]; int lds8[8];
#pragma unroll
    for (int s = 0; s < 8; ++s) {
        int ht = s >> 1, g2 = s & 1;
        int opB = ht & 1, half = ht >> 1;
        int local = half * 16384 + g2 * 8192 + tid * 16;
        int row = local >> 7;
        int c = local & 127;
        int ce = (c ^ ((row & 7) << 4)) >> 1;
        lds8[s] = opB * 32768 + local;
        gb[s] = (size_t)((opB ? bn0 : bm0) + row) * K2 + ce;
    }

    f32x4 acc[8][4];
#pragma unroll
    for (int i = 0; i < 8; ++i)
#pragma unroll
        for (int j = 0; j < 4; ++j) {
            acc[i][j][0] = 0.f; acc[i][j][1] = 0.f; acc[i][j][2] = 0.f; acc[i][j][3] = 0.f;
        }

    // segment remap for K-tile tt (64 logical k per tile)
    auto segoffs = [&](int tt, int& oA, int& oB) {
        int ksub = tt << 6;
        int seg = (ksub >= K ? 1 : 0) + (ksub >= K2 ? 1 : 0);
        int tcol = ksub - seg * K;
        oA = (seg == 1 ? K : 0) + tcol;
        oB = (seg == 2 ? K : 0) + tcol;
    };

    // prologue: stage tile 0 into buf 0
    {
        int oA0, oB0; segoffs(0, oA0, oB0);
        ISSUE8(0, 0, oA0, oB0); ISSUE8(1, 0, oA0, oB0);
        ISSUE8(2, 0, oA0, oB0); ISSUE8(3, 0, oA0, oB0);
        ISSUE8(4, 0, oA0, oB0); ISSUE8(5, 0, oA0, oB0);
        ISSUE8(6, 0, oA0, oB0); ISSUE8(7, 0, oA0, oB0);
    }
    asm volatile("s_waitcnt vmcnt(4)" ::: "memory");   // H0,H1 of tile 0 landed
    barx();

    bf16x8 a0[4][2], a1[4][2], b0[2][2], b1[2][2];

    for (int t = 0; t < NT; ++t) {
        const int rb = t & 1, wb = rb ^ 1;
        const bool more = (t + 1) < NT;
        int oAn = 0, oBn = 0;
        if (more) segoffs(t + 1, oAn, oBn);

        // ---- P1: quad(0,0) ---- reads A-half0 + B-half0; prefetch H0(t+1)
        RD_A8(a0[0], 0, rb); RD_A8(a0[1], 1, rb); RD_A8(a0[2], 2, rb); RD_A8(a0[3], 3, rb);
        RD_B8(b0[0], 0, rb); RD_B8(b0[1], 1, rb);
        if (more) { ISSUE8(0, wb, oAn, oBn); ISSUE8(1, wb, oAn, oBn); }
        if (more) { asm volatile("s_waitcnt vmcnt(2)" ::: "memory"); }  // H2,H3(t) landed
        else      { asm volatile("s_waitcnt vmcnt(0)" ::: "memory"); }
        barx();
        __builtin_amdgcn_s_setprio(1);
        MM8(0, 0, a0, b0);
        __builtin_amdgcn_s_setprio(0);
        barx();

        // ---- P2: quad(0,1) ---- reads B-half1; prefetch H1(t+1)
        RD_B8(b1[0], 2, rb); RD_B8(b1[1], 3, rb);
        if (more) { ISSUE8(2, wb, oAn, oBn); ISSUE8(3, wb, oAn, oBn); }
        barx();
        __builtin_amdgcn_s_setprio(1);
        MM8(0, 1, a0, b1);
        __builtin_amdgcn_s_setprio(0);
        barx();

        // ---- P3: quad(1,0) ---- reads A-half1; prefetch H2(t+1)
        RD_A8(a1[0], 4, rb); RD_A8(a1[1], 5, rb); RD_A8(a1[2], 6, rb); RD_A8(a1[3], 7, rb);
        if (more) { ISSUE8(4, wb, oAn, oBn); ISSUE8(5, wb, oAn, oBn); }
        barx();
        __builtin_amdgcn_s_setprio(1);
        MM8(1, 0, a1, b0);
        __builtin_amdgcn_s_setprio(0);
        barx();

        // ---- P4: quad(1,1) ---- no new reads; prefetch H3(t+1); wait H0,H1(t+1)
        if (more) { ISSUE8(6, wb, oAn, oBn); ISSUE8(7, wb, oAn, oBn); }
        if (more) { asm volatile("s_waitcnt vmcnt(4)" ::: "memory"); }
        else      { asm volatile("s_waitcnt vmcnt(0)" ::: "memory"); }
        barx();
        __builtin_amdgcn_s_setprio(1);
        MM8(1, 1, a1, b1);
        __builtin_amdgcn_s_setprio(0);
        barx();
    }

    // epilogue: frag (m,n) covers C rows (m*2+wr)*16.., cols (n*4+wc)*16..
#pragma unroll
    for (int n = 0; n < 4; ++n) {
        int col = bn0 + (n * 4 + wc) * 16 + rl;
        float bv = bias[col];
#pragma unroll
        for (int m = 0; m < 8; ++m) {
            int row0 = bm0 + (m * 2 + wr) * 16 + g * 4;
#pragma unroll
            for (int q = 0; q < 4; ++q) {
                int row = row0 + q;
                float v = acc[m][n][q] + bv;
                if (EPI == 0) {
                    Cf[(size_t)row * N + col] = fmaxf(v, 0.f);
                } else if (EPI == 1) {
                    float rv = fmaxf(v, 0.f);
                    u16 hi = f32_bf16_rne(rv);
                    u16 lo = f32_bf16_rne(rv - bf16_f32(hi));
                    Cs[(size_t)row * (2 * N) + col] = hi;
                    Cs[(size_t)row * (2 * N) + N + col] = lo;
                } else {
                    if (row < Mvalid) Cf[(size_t)row * N + col] = v;
                }
            }
        }
    }
}

// ---------------- launch ----------------

static inline size_t align_up(size_t x, size_t a) { return (x + a - 1) & ~(a - 1); }

extern "C" void kernel_launch(void* const* d_in, const int* in_sizes, int n_in,
                              void* d_out, int out_size, void* d_ws, size_t ws_size,
                              hipStream_t stream) {
    const int*   edge_index = (const int*)d_in[0];
    const float* node = (const float*)d_in[1];
    const float* W1 = (const float*)d_in[2];
    const float* b1 = (const float*)d_in[3];
    const float* W2 = (const float*)d_in[4];
    const float* b2 = (const float*)d_in[5];
    const float* W3 = (const float*)d_in[6];
    const float* b3 = (const float*)d_in[7];
    const float* Wfc = (const float*)d_in[8];
    const float* bfc = (const float*)d_in[9];
    float* out = (float*)d_out;

    const int E = in_sizes[0] / 2;   // 400000
    const int NV = NNODES;
    const int P = PADM;

    // allow 128 KiB dynamic LDS (idempotent; persists for captured launches)
    (void)hipFuncSetAttribute((const void*)k_gemm8<0>, hipFuncAttributeMaxDynamicSharedMemorySize, 131072);
    (void)hipFuncSetAttribute((const void*)k_gemm8<1>, hipFuncAttributeMaxDynamicSharedMemorySize, 131072);
    (void)hipFuncSetAttribute((const void*)k_gemm8<2>, hipFuncAttributeMaxDynamicSharedMemorySize, 131072);

    // workspace layout
    char* ws = (char*)d_ws;
    size_t off = 0;
    int* cnt = (int*)(ws + off);          off = align_up(off + (size_t)NV * 4, 1024);
    int* offs = (int*)(ws + off);         off = align_up(off + (size_t)(NV + 1) * 4, 1024);
    int* cursor = (int*)(ws + off);       off = align_up(off + (size_t)NV * 4, 1024);
    float* dinv = (float*)(ws + off);     off = align_up(off + (size_t)NV * 4, 1024);
    int* csr_src = (int*)(ws + off);      off = align_up(off + (size_t)E * 4, 1024);
    float* csr_w = (float*)(ws + off);    off = align_up(off + (size_t)E * 4, 1024);
    u16* W1s = (u16*)(ws + off);          off = align_up(off + (size_t)128 * 256 * 2, 1024);
    u16* W2s = (u16*)(ws + off);          off = align_up(off + (size_t)256 * 256 * 2, 1024);
    u16* W3s = (u16*)(ws + off);          off = align_up(off + (size_t)512 * 512 * 2, 1024);
    u16* Wfcs = (u16*)(ws + off);         off = align_up(off + (size_t)1024 * 1024 * 2, 1024);
    u16* A1s = (u16*)(ws + off);          off = align_up(off + (size_t)P * 256 * 2, 1024);
    u16* A3s = (u16*)(ws + off);          off = align_up(off + (size_t)P * 512 * 2, 1024);
    u16* A4s = (u16*)(ws + off);          off = align_up(off + (size_t)P * 1024 * 2, 1024);
    float* xbuf1 = (float*)(ws + off);    off = align_up(off + (size_t)P * 128 * 4, 1024);
    float* xbuf2 = (float*)(ws + off);    off = align_up(off + (size_t)P * 256 * 4, 1024);

    const int* src = edge_index;
    const int* dst = edge_index + E;

    // weight splits
    k_splitW<<<(128 * 128 + 255) / 256, 256, 0, stream>>>(W1, W1s, 128 * 128, 128);
    k_splitW<<<(256 * 128 + 255) / 256, 256, 0, stream>>>(W2, W2s, 256 * 128, 128);
    k_splitW<<<(512 * 256 + 255) / 256, 256, 0, stream>>>(W3, W3s, 512 * 256, 256);
    k_splitW<<<(1024 * 512 + 255) / 256, 256, 0, stream>>>(Wfc, Wfcs, 1024 * 512, 512);

    // CSR build
    k_zero_cnt<<<(NV + 255) / 256, 256, 0, stream>>>(cnt, NV);
    k_count<<<(E + 255) / 256, 256, 0, stream>>>(dst, E, cnt);
    k_dinv<<<(NV + 255) / 256, 256, 0, stream>>>(cnt, dinv, NV);
    k_scan<<<1, 1024, 0, stream>>>(cnt, NV, offs, cursor);
    k_fill<<<(E + 255) / 256, 256, 0, stream>>>(src, dst, E, cursor, dinv, csr_src, csr_w);

    dim3 blk(256);
    int aggGrid = P / 4;
    const int nbx = P / 128;    // 392
    const int nbm8 = P / 256;   // 196

    // layer 1: agg -> A1s, 128-tile gemm -> xbuf1
    k_aggregate_split<128><<<aggGrid, blk, 0, stream>>>(node, offs, csr_src, csr_w, dinv, A1s, NV, P);
    k_mfma_gemm<0><<<nbx * 1, blk, 0, stream>>>(A1s, W1s, b1, xbuf1, nullptr, 128, 128, P, 1);

    // layer 2: agg -> A1s, 8-phase gemm (N=256,K=128) -> xbuf2
    k_aggregate_split<128><<<aggGrid, blk, 0, stream>>>(xbuf1, offs, csr_src, csr_w, dinv, A1s, NV, P);
    k_gemm8<0><<<nbm8 * 1, 512, 131072, stream>>>(A1s, W2s, b2, xbuf2, nullptr, 256, 128, P, 1);

    // layer 3: agg -> A3s, 8-phase gemm (N=512,K=256) -> A4s (split-bf16)
    k_aggregate_split<256><<<aggGrid, blk, 0, stream>>>(xbuf2, offs, csr_src, csr_w, dinv, A3s, NV, P);
    k_gemm8<1><<<nbm8 * 2, 512, 131072, stream>>>(A3s, W3s, b3, nullptr, A4s, 512, 256, P, 2);

    // FC: 8-phase gemm (N=1024,K=512) -> out (f32, rows < NV)
    k_gemm8<2><<<nbm8 * 4, 512, 131072, stream>>>(A4s, Wfcs, bfc, out, nullptr, 1024, 512, NV, 4);
}